// Round 1
// 237.439 us; speedup vs baseline: 1.0855x; 1.0855x over previous
//
#include <hip/hip_runtime.h>
#include <stdint.h>

// ConcatLayer_55654186221983 on MI355X (gfx950). All fp32 I/O.
// B=8, C=128, C2=256, H=W=64, EMB=512, GROUPS=32, EPS=1e-5.
// R10: gn1 merged into prep (shfl reduction); gn2a killed (GN2+FiLM+SiLU
//      fused into conv2 staging from NCHW fp32); c2 write/read replaced by
//      in-register pooled c2-half; fast silu (v_exp+v_rcp). 7 -> 5 dispatches.

#define B_   8
#define C_   128
#define C2_  256
#define HW_  4096
#define EMB_ 512
#define EPS_ 1e-5f

typedef int   v16i __attribute__((ext_vector_type(16)));
typedef float v16f __attribute__((ext_vector_type(16)));
typedef short v8s  __attribute__((ext_vector_type(8)));
typedef int   v4i  __attribute__((ext_vector_type(4)));

// LDS tile: 3 rows x 66 cols x (256 data + 16 pad) bytes
#define COLB 272
#define LDSZ (3 * 66 * COLB)

__device__ __forceinline__ float silu(float v) {
    // native v_exp_f32 + v_rcp_f32 (~2 ulp; dwarfed by bf16 rounding downstream)
    return v * __builtin_amdgcn_rcpf(1.f + __expf(-v));
}
__device__ __forceinline__ unsigned short f2bf(float f) {
    unsigned int x = __float_as_uint(f);
    return (unsigned short)((x + 0x7FFFu + ((x >> 16) & 1u)) >> 16);  // RNE
}
__device__ __forceinline__ int8_t sgn8(float v) {
    return (v > 0.f) ? (int8_t)1 : ((v < 0.f) ? (int8_t)(-1) : (int8_t)0);
}

// ---- merged prep + embedding + GN1:
// blocks 0..127: binary weights + alpha + zero bnS/bnQ/gnS/gnQ
// blocks 128..703: conv weight relayout
// blocks 704..895: embedding MLPs (wave per output row)
// blocks 896..1151: GN1 stats + apply + SiLU + NCHW->NHWC bf16 (one block per (n,grp))
__global__ __launch_bounds__(256) void k_prep(
    const float* __restrict__ w, int8_t* __restrict__ sgn,
    float* __restrict__ alpha, float* __restrict__ bnS, float* __restrict__ bnQ,
    float* __restrict__ gnS, float* __restrict__ gnQ,
    const float* __restrict__ w1, const float* __restrict__ w2,
    unsigned short* __restrict__ Wc1, unsigned short* __restrict__ Wc2,
    const float* __restrict__ emb,
    const float* __restrict__ ew, const float* __restrict__ ebb,
    const float* __restrict__ m1w, const float* __restrict__ m1b,
    const float* __restrict__ m2w, const float* __restrict__ m2b,
    const float* __restrict__ m3w, const float* __restrict__ m3b,
    float* __restrict__ eo, float* __restrict__ b1,
    float* __restrict__ b2, float* __restrict__ b3,
    const float* __restrict__ gin, const float* __restrict__ g1w,
    const float* __restrict__ g1b, unsigned short* __restrict__ act1) {
    __shared__ float red[256];
    const int blk = blockIdx.x, tid = threadIdx.x;
    if (blk < 128) {
        const int o = blk;
        if (o == 0 && tid < 128) { bnS[tid] = 0.f; bnQ[tid] = 0.f; }
        if (o == 1) { gnS[tid] = 0.f; }           // 256 floats
        if (o == 2) { gnQ[tid] = 0.f; }
        const float* wr = w + (size_t)o * (C2_ * 9);
        float s = 0.f;
        for (int i = tid; i < C2_ * 9; i += 256) s += fabsf(wr[i]);
        red[tid] = s;
        __syncthreads();
        for (int st = 128; st > 0; st >>= 1) {
            if (tid < st) red[tid] += red[tid + st];
            __syncthreads();
        }
        if (tid == 0) alpha[o] = red[0] / (float)(C2_ * 9);
        for (int kk = 0; kk < 9; ++kk) {
            float v = wr[tid * 9 + kk];   // tid == ci
            sgn[((size_t)(kk * 16 + (tid >> 4)) * C_ + o) * 16 + (tid & 15)] = sgn8(v);
        }
    } else if (blk < 704) {
        int i = (blk - 128) * 256 + tid;
        int co = i / (C_ * 9);
        int rem = i - co * (C_ * 9);
        int ci = rem / 9, kk = rem - ci * 9;
        size_t d = ((size_t)(kk * 16 + (ci >> 3)) * C_ + co) * 8 + (ci & 7);
        Wc1[d] = f2bf(w1[i]);
        Wc2[d] = f2bf(w2[i]);
    } else if (blk < 896) {
        const int o = (blk - 704) * 4 + (tid >> 6);   // wave-uniform, 0..767
        const int l = tid & 63;
        const float* wv;
        float bias;
        float* dst;
        int dstride;
        if (o < 256)      { wv = ew  + (size_t)o * EMB_;              bias = ebb[o];    dst = eo + o;  dstride = 256; }
        else if (o < 512) { int r = o - 256; wv = m1w + (size_t)r * EMB_; bias = m1b[r]; dst = b1 + r; dstride = 256; }
        else if (o < 640) { int r = o - 512; wv = m2w + (size_t)r * EMB_; bias = m2b[r]; dst = b2 + r; dstride = 128; }
        else              { int r = o - 640; wv = m3w + (size_t)r * EMB_; bias = m3b[r]; dst = b3 + r; dstride = 128; }
        const float4 wa = *(const float4*)(wv + 8 * l);
        const float4 wb = *(const float4*)(wv + 8 * l + 4);
#pragma unroll
        for (int b = 0; b < B_; ++b) {
            const float* s = emb + b * EMB_ + 8 * l;
            float4 sa = *(const float4*)(s);
            float4 sb = *(const float4*)(s + 4);
            float p = wa.x * silu(sa.x) + wa.y * silu(sa.y) + wa.z * silu(sa.z) + wa.w * silu(sa.w) +
                      wb.x * silu(sb.x) + wb.y * silu(sb.y) + wb.z * silu(sb.z) + wb.w * silu(sb.w);
#pragma unroll
            for (int off = 32; off > 0; off >>= 1) p += __shfl_down(p, off, 64);
            if (l == 0) dst[b * dstride] = bias + p;
        }
    } else {
        // GN1: one block per (n,grp), 256 threads, shfl-based reduction
        const int bb = blk - 896;
        const int n = bb >> 5, grp = bb & 31;
        const size_t base = ((size_t)(n * C_ + grp * 4)) << 12;
        float sum = 0.f, sq = 0.f;
        const float4* in4 = (const float4*)(gin + base);
        for (int i = tid; i < 4096; i += 256) {
            float4 v = in4[i];
            sum += v.x + v.y + v.z + v.w;
            sq += v.x * v.x + v.y * v.y + v.z * v.z + v.w * v.w;
        }
#pragma unroll
        for (int off = 32; off > 0; off >>= 1) {
            sum += __shfl_xor(sum, off, 64);
            sq  += __shfl_xor(sq, off, 64);
        }
        if ((tid & 63) == 0) { red[tid >> 6] = sum; red[8 + (tid >> 6)] = sq; }
        __syncthreads();
        sum = red[0] + red[1] + red[2] + red[3];
        sq  = red[8] + red[9] + red[10] + red[11];
        const float mu = sum * (1.f / 16384.f);
        const float rstd = rsqrtf(sq * (1.f / 16384.f) - mu * mu + EPS_);
        float gg[4], bb4[4];
#pragma unroll
        for (int j = 0; j < 4; ++j) { gg[j] = g1w[grp * 4 + j]; bb4[j] = g1b[grp * 4 + j]; }
        for (int hw = tid; hw < HW_; hw += 256) {
            union { unsigned short u[4]; uint2 v; } pk;
#pragma unroll
            for (int j = 0; j < 4; ++j) {
                float v = gin[base + ((size_t)j << 12) + hw];
                pk.u[j] = f2bf(silu((v - mu) * rstd * gg[j] + bb4[j]));
            }
            *(uint2*)(act1 + ((size_t)(n * HW_ + hw)) * C_ + grp * 4) = pk.v;
        }
    }
}

// ---- shared LDS row-staging: 3 rows x 64 cols of 256B -> padded cols 1..64 ----
__device__ __forceinline__ void stage_rows(char* lds, const char* rs0,
                                           const char* rs1, const char* rs2) {
    const int tid = threadIdx.x;
    const char* rs[3] = {rs0, rs1, rs2};
    if (tid < 96) {
        int r = tid / 32, q = tid & 31;
        int c = (q >> 4) ? 65 : 0, o = q & 15;
        *(float4*)(lds + (r * 66 + c) * COLB + o * 16) = make_float4(0.f, 0.f, 0.f, 0.f);
    }
#pragma unroll
    for (int u = 0; u < 12; ++u) {
        int idx = u * 256 + tid;
        int r = idx >> 10, rem = idx & 1023;
        int x = rem >> 4, o = rem & 15;
        char* dst = lds + (r * 66 + x + 1) * COLB + o * 16;
        if (rs[r]) *(float4*)dst = *(const float4*)(rs[r] + x * 256 + o * 16);
        else       *(float4*)dst = make_float4(0.f, 0.f, 0.f, 0.f);
    }
}

// ---- conv1: bf16 MFMA implicit-GEMM + fused GN2 stats (unchanged) ----
__global__ __launch_bounds__(256) void k_conv1(const unsigned short* __restrict__ act,
                                               const unsigned short* __restrict__ Wc,
                                               const float* __restrict__ bias,
                                               float* __restrict__ out,
                                               float* __restrict__ gnS,
                                               float* __restrict__ gnQ) {
    __shared__ __align__(16) char lds[LDSZ];
    const int y = blockIdx.x;
    const int n = blockIdx.y;
    const char* base = (const char*)(act + ((size_t)n * 64) * 64 * C_);
    stage_rows(lds,
               (y > 0)  ? base + (size_t)(y - 1) * 16384 : nullptr,
               base + (size_t)y * 16384,
               (y < 63) ? base + (size_t)(y + 1) * 16384 : nullptr);
    __syncthreads();

    const int w = threadIdx.x >> 6;
    const int l = threadIdx.x & 63;
    const int lm = l & 31;
    const int lh = l >> 5;

    v16f acc0, acc1;
#pragma unroll
    for (int i = 0; i < 16; ++i) { acc0[i] = 0.f; acc1[i] = 0.f; }

#pragma unroll
    for (int kk = 0; kk < 9; ++kk) {
        const int r = kk / 3, dx = kk % 3 - 1;
        const char* col0 = lds + (r * 66 + lm + 1 + dx) * COLB + 16 * lh;
        const char* col1 = col0 + 32 * COLB;
        const unsigned short* wbase = Wc + (size_t)(kk * 16 + lh) * C_ * 8 + (32 * w + lm) * 8;
#pragma unroll
        for (int cb = 0; cb < 8; ++cb) {
            v8s a = *(const v8s*)(wbase + (size_t)(2 * cb) * C_ * 8);
            v8s b0 = *(const v8s*)(col0 + 32 * cb);
            v8s b1 = *(const v8s*)(col1 + 32 * cb);
            acc0 = __builtin_amdgcn_mfma_f32_32x32x16_bf16(a, b0, acc0, 0, 0, 0);
            acc1 = __builtin_amdgcn_mfma_f32_32x32x16_bf16(a, b1, acc1, 0, 0, 0);
        }
    }
    float pr[16], qr[16];
#pragma unroll
    for (int r = 0; r < 16; ++r) {
        const int row = (r & 3) + 8 * (r >> 2) + 4 * lh;
        const int co = 32 * w + row;
        const float bv = bias[co];
        const size_t o = (((size_t)n * C_ + co) << 12) + (y << 6);
        float v0 = acc0[r] + bv, v1 = acc1[r] + bv;
        out[o + lm] = v0;
        out[o + 32 + lm] = v1;
        pr[r] = v0 + v1;
        qr[r] = v0 * v0 + v1 * v1;
    }
    // fused GN2 stats: per-channel partials -> per-group atomics
    __syncthreads();
    float* ldsS = (float*)lds;
    float* ldsQ = (float*)lds + 128;
#pragma unroll
    for (int r = 0; r < 16; ++r) {
        float p = pr[r], q = qr[r];
#pragma unroll
        for (int m = 16; m > 0; m >>= 1) {
            p += __shfl_xor(p, m, 64);
            q += __shfl_xor(q, m, 64);
        }
        if (lm == 0) {
            const int row = (r & 3) + 8 * (r >> 2) + 4 * lh;
            const int co = 32 * w + row;
            ldsS[co] = p;
            ldsQ[co] = q;
        }
    }
    __syncthreads();
    if (threadIdx.x < 32) {
        const int g = threadIdx.x;
        float p = ldsS[4 * g] + ldsS[4 * g + 1] + ldsS[4 * g + 2] + ldsS[4 * g + 3];
        float q = ldsQ[4 * g] + ldsQ[4 * g + 1] + ldsQ[4 * g + 2] + ldsQ[4 * g + 3];
        atomicAdd(&gnS[n * 32 + g], p);
        atomicAdd(&gnQ[n * 32 + g], q);
    }
}

// ---- conv2: GN2+FiLM+SiLU fused into staging (reads conv1 NCHW fp32),
//      bf16 MFMA + residual + fused sign+transpose + pooled c2-half ----
__global__ __launch_bounds__(256) void k_conv2(const float* __restrict__ yin,
                                               const unsigned short* __restrict__ Wc,
                                               const float* __restrict__ bias,
                                               const float* __restrict__ res,
                                               const float* __restrict__ xin,
                                               const float* __restrict__ b1v,
                                               const float* __restrict__ eo,
                                               const float* __restrict__ g2,
                                               const float* __restrict__ bt2,
                                               const float* __restrict__ gnS,
                                               const float* __restrict__ gnQ,
                                               float* __restrict__ poolC2,
                                               int8_t* __restrict__ S) {
    __shared__ __align__(16) char lds[LDSZ];
    __shared__ float ldsA[128], ldsB[128];
    const int y = blockIdx.x;
    const int n = blockIdx.y;
    const int tid = threadIdx.x;

    // per-channel GN2*FiLM affine: y = v*A + B (then silu, then bf16)
    if (tid < 128) {
        const int ch = tid, grp = tid >> 2;
        const float mu = gnS[n * 32 + grp] * (1.f / 16384.f);
        const float var = gnQ[n * 32 + grp] * (1.f / 16384.f) - mu * mu;
        const float rstd = rsqrtf(var + EPS_);
        const float gg = g2[ch] * rstd;
        const float sc = 1.f + eo[n * 256 + ch];
        ldsA[ch] = gg * sc;
        ldsB[ch] = (bt2[ch] - mu * gg) * sc + eo[n * 256 + 128 + ch];
    }
    if (tid < 96) {   // zero pad columns 0 and 65
        int r = tid / 32, q = tid & 31;
        int cpad = (q >> 4) ? 65 : 0, o = q & 15;
        *(float4*)(lds + (r * 66 + cpad) * COLB + o * 16) = make_float4(0.f, 0.f, 0.f, 0.f);
    }
    __syncthreads();

    // staging with transform: 3 rows x 128 ch x 64 px, NCHW fp32 source.
    // px = seg + 16*j keeps the transposing u16 LDS writes at ~4-way conflict.
    const float* yb = yin + ((size_t)n * C_) * HW_ + (y << 6);
#pragma unroll 4
    for (int u = 0; u < 24; ++u) {
        int unit = u * 256 + tid;
        int r = unit >> 11, rem = unit & 2047;
        int ch = rem >> 4, seg = rem & 15;
        int yy = y - 1 + r;
        char* dst = lds + (r * 66 + 1 + seg) * COLB + ch * 2;
        if (yy >= 0 && yy < 64) {
            const float A = ldsA[ch], Bv = ldsB[ch];
            const float* src = yb + (size_t)ch * HW_ + (r - 1) * 64 + seg;
#pragma unroll
            for (int j = 0; j < 4; ++j)
                *(unsigned short*)(dst + (16 * j) * COLB) = f2bf(silu(src[16 * j] * A + Bv));
        } else {
#pragma unroll
            for (int j = 0; j < 4; ++j)
                *(unsigned short*)(dst + (16 * j) * COLB) = 0;
        }
    }
    __syncthreads();

    const int w = tid >> 6;
    const int l = tid & 63;
    const int lm = l & 31;
    const int lh = l >> 5;

    v16f acc0, acc1;
#pragma unroll
    for (int i = 0; i < 16; ++i) { acc0[i] = 0.f; acc1[i] = 0.f; }

#pragma unroll
    for (int kk = 0; kk < 9; ++kk) {
        const int r = kk / 3, dx = kk % 3 - 1;
        const char* col0 = lds + (r * 66 + lm + 1 + dx) * COLB + 16 * lh;
        const char* col1 = col0 + 32 * COLB;
        const unsigned short* wbase = Wc + (size_t)(kk * 16 + lh) * C_ * 8 + (32 * w + lm) * 8;
#pragma unroll
        for (int cb = 0; cb < 8; ++cb) {
            v8s a = *(const v8s*)(wbase + (size_t)(2 * cb) * C_ * 8);
            v8s b0 = *(const v8s*)(col0 + 32 * cb);
            v8s b1 = *(const v8s*)(col1 + 32 * cb);
            acc0 = __builtin_amdgcn_mfma_f32_32x32x16_bf16(a, b0, acc0, 0, 0, 0);
            acc1 = __builtin_amdgcn_mfma_f32_32x32x16_bf16(a, b1, acc1, 0, 0, 0);
        }
    }
    float c2v0[16], c2v1[16];
#pragma unroll
    for (int r = 0; r < 16; ++r) {
        const int row = (r & 3) + 8 * (r >> 2) + 4 * lh;
        const int co = 32 * w + row;
        const float bv = bias[co];
        const size_t o = (((size_t)n * C_ + co) << 12) + (y << 6);
        c2v0[r] = acc0[r] + bv + res[o + lm];
        c2v1[r] = acc1[r] + bv + res[o + 32 + lm];
    }
    // pooled c2-half: mean over adjacent channel pairs, in-register.
    // c2 channel co = 32w + (r&3) + 8q + 4lh; pairs live in adjacent r slots.
#pragma unroll
    for (int q = 0; q < 4; ++q) {
        const int pc = 16 * w + 4 * q + 2 * lh;   // pooled channel (0..63)
        const size_t po = (((size_t)n * 64 + pc) << 12) + (y << 6);
        poolC2[po + lm]             = 0.5f * (c2v0[4 * q] + c2v0[4 * q + 1]);
        poolC2[po + 32 + lm]        = 0.5f * (c2v1[4 * q] + c2v1[4 * q + 1]);
        poolC2[po + 4096 + lm]      = 0.5f * (c2v0[4 * q + 2] + c2v0[4 * q + 3]);
        poolC2[po + 4096 + 32 + lm] = 0.5f * (c2v1[4 * q + 2] + c2v1[4 * q + 3]);
    }

    // ---- fused sign: build S row [64 px][256 ch] bytes in LDS, then store ----
    __syncthreads();                 // staging LDS fully consumed
    // c2 half: pack 4 consecutive channels per u32 (rows r&3 are consecutive)
#pragma unroll
    for (int q = 0; q < 4; ++q) {
        const int co0 = 32 * w + 8 * q + 4 * lh;
        const float b0 = b1v[n * 256 + 128 + co0];
        const float b1b = b1v[n * 256 + 128 + co0 + 1];
        const float b2b = b1v[n * 256 + 128 + co0 + 2];
        const float b3b = b1v[n * 256 + 128 + co0 + 3];
        union { int8_t b[4]; int u; } p0, p1;
        p0.b[0] = sgn8(c2v0[4 * q] + b0);  p1.b[0] = sgn8(c2v1[4 * q] + b0);
        p0.b[1] = sgn8(c2v0[4 * q + 1] + b1b); p1.b[1] = sgn8(c2v1[4 * q + 1] + b1b);
        p0.b[2] = sgn8(c2v0[4 * q + 2] + b2b); p1.b[2] = sgn8(c2v1[4 * q + 2] + b2b);
        p0.b[3] = sgn8(c2v0[4 * q + 3] + b3b); p1.b[3] = sgn8(c2v1[4 * q + 3] + b3b);
        *(int*)(lds + lm * COLB + 128 + co0) = p0.u;
        *(int*)(lds + (32 + lm) * COLB + 128 + co0) = p1.u;
    }
    // x half: 128 ch x 16 float4-segments
#pragma unroll
    for (int u = 0; u < 8; ++u) {
        int idx = u * 256 + tid;
        int ch = idx >> 4, seg = idx & 15;
        float4 v = *(const float4*)(xin + (((size_t)(n * C_ + ch)) << 12) + (y << 6) + 4 * seg);
        const float bv = b1v[n * 256 + ch];
        lds[(4 * seg) * COLB + ch]     = sgn8(v.x + bv);
        lds[(4 * seg + 1) * COLB + ch] = sgn8(v.y + bv);
        lds[(4 * seg + 2) * COLB + ch] = sgn8(v.z + bv);
        lds[(4 * seg + 3) * COLB + ch] = sgn8(v.w + bv);
    }
    __syncthreads();
    int8_t* Srow = S + ((size_t)(n * HW_) + (y << 6)) * C2_;
#pragma unroll
    for (int u = 0; u < 4; ++u) {
        int idx = u * 256 + tid;
        int px = idx >> 4, c16 = idx & 15;
        *(int4*)(Srow + (size_t)px * C2_ + 16 * c16) = *(const int4*)(lds + px * COLB + 16 * c16);
    }
}

// ---- binary conv: i8 K=32 MFMA implicit GEMM + fused BN stats (unchanged) ----
__global__ __launch_bounds__(256) void k_bconv(const int8_t* __restrict__ S,
                                               const int8_t* __restrict__ Wk,
                                               const float* __restrict__ alpha,
                                               const float* __restrict__ bias,
                                               float* __restrict__ out,
                                               float* __restrict__ bnS,
                                               float* __restrict__ bnQ) {
    __shared__ __align__(16) char lds[LDSZ];
    const int y = blockIdx.x;
    const int n = blockIdx.y;
    const char* base = (const char*)(S + ((size_t)n * 64) * 64 * C2_);
    stage_rows(lds,
               (y > 0)  ? base + (size_t)(y - 1) * 16384 : nullptr,
               base + (size_t)y * 16384,
               (y < 63) ? base + (size_t)(y + 1) * 16384 : nullptr);
    __syncthreads();

    const int w = threadIdx.x >> 6;
    const int l = threadIdx.x & 63;
    const int lm = l & 31;
    const int lh = l >> 5;

    v16i acc0, acc1;
#pragma unroll
    for (int i = 0; i < 16; ++i) { acc0[i] = 0; acc1[i] = 0; }

#pragma unroll
    for (int kk = 0; kk < 9; ++kk) {
        const int r = kk / 3, dx = kk % 3 - 1;
        const char* col0 = lds + (r * 66 + lm + 1 + dx) * COLB + 16 * lh;
        const char* col1 = col0 + 32 * COLB;
        const int8_t* wbase = Wk + (size_t)(kk * 16 + lh) * C_ * 16 + (32 * w + lm) * 16;
#pragma unroll
        for (int s = 0; s < 8; ++s) {
            v4i a = *(const v4i*)(wbase + (size_t)(2 * s) * C_ * 16);
            v4i b0 = *(const v4i*)(col0 + 32 * s);
            v4i b1 = *(const v4i*)(col1 + 32 * s);
            acc0 = __builtin_amdgcn_mfma_i32_32x32x32_i8(a, b0, acc0, 0, 0, 0);
            acc1 = __builtin_amdgcn_mfma_i32_32x32x32_i8(a, b1, acc1, 0, 0, 0);
        }
    }

    float pr[16], qr[16];
#pragma unroll
    for (int r = 0; r < 16; ++r) {
        const int row = (r & 3) + 8 * (r >> 2) + 4 * lh;
        const int co = 32 * w + row;
        const float av = alpha[co], bv = bias[co];
        const size_t o = (((size_t)n * C_ + co) << 12) + (y << 6);
        float v0 = av * (float)acc0[r] + bv;
        float v1 = av * (float)acc1[r] + bv;
        out[o + lm]      = v0;
        out[o + 32 + lm] = v1;
        pr[r] = v0 + v1;
        qr[r] = v0 * v0 + v1 * v1;
    }
    __syncthreads();
    float* ldsS = (float*)lds;
    float* ldsQ = (float*)lds + 128;
#pragma unroll
    for (int r = 0; r < 16; ++r) {
        float p = pr[r], q = qr[r];
#pragma unroll
        for (int m = 16; m > 0; m >>= 1) {
            p += __shfl_xor(p, m, 64);
            q += __shfl_xor(q, m, 64);
        }
        if (lm == 0) {
            const int row = (r & 3) + 8 * (r >> 2) + 4 * lh;
            const int co = 32 * w + row;
            ldsS[co] = p;
            ldsQ[co] = q;
        }
    }
    __syncthreads();
    if (threadIdx.x < 128) {
        atomicAdd(&bnS[threadIdx.x], ldsS[threadIdx.x]);
        atomicAdd(&bnQ[threadIdx.x], ldsQ[threadIdx.x]);
    }
}

// ---- final epilogue, float4; c2-half pooling pre-averaged by conv2 ----
__global__ __launch_bounds__(256) void k_final(const float* __restrict__ y3,
                                               const float* __restrict__ x,
                                               const float* __restrict__ poolC2,
                                               const float* __restrict__ bnS,
                                               const float* __restrict__ bnQ,
                                               const float* __restrict__ bng,
                                               const float* __restrict__ bnb,
                                               const float* __restrict__ b2v,
                                               const float* __restrict__ pa,
                                               const float* __restrict__ b3v,
                                               float* __restrict__ out) {
    const int idx4 = blockIdx.x * 256 + threadIdx.x;   // < 1,048,576
    const int hw = (idx4 & 1023) * 4;
    const int cb = idx4 >> 10;
    const int co = cb & 127;
    const int n = cb >> 7;
    const float mu = bnS[co] * (1.f / 32768.f);
    const float var = bnQ[co] * (1.f / 32768.f) - mu * mu;
    const float rstd = rsqrtf(var + EPS_);
    const float gm = rstd * bng[co];
    const float bt = bnb[co] - mu * gm;
    const size_t obase = (((size_t)(n * C_ + co)) << 12) + hw;
    float4 v = *(const float4*)(y3 + obase);
    v.x = v.x * gm + bt; v.y = v.y * gm + bt; v.z = v.z * gm + bt; v.w = v.w * gm + bt;

    float4 pv;
    if (co < 64) {
        const int ch0 = 2 * co;
        float4 pA = *(const float4*)(x + (((size_t)(n * C_ + ch0)) << 12) + hw);
        float4 pB = *(const float4*)(x + (((size_t)(n * C_ + ch0 + 1)) << 12) + hw);
        pv.x = 0.5f * (pA.x + pB.x); pv.y = 0.5f * (pA.y + pB.y);
        pv.z = 0.5f * (pA.z + pB.z); pv.w = 0.5f * (pA.w + pB.w);
    } else {
        pv = *(const float4*)(poolC2 + (((size_t)(n * 64 + co - 64)) << 12) + hw);
    }
    const float bias2 = b2v[n * 128 + co];
    const float aP = pa[co];
    const float bias3 = b3v[n * 128 + co];
    float4 r;
    float t;
    t = v.x + pv.x + bias2; t = (t >= 0.f) ? t : aP * t; r.x = t + bias3;
    t = v.y + pv.y + bias2; t = (t >= 0.f) ? t : aP * t; r.y = t + bias3;
    t = v.z + pv.z + bias2; t = (t >= 0.f) ? t : aP * t; r.z = t + bias3;
    t = v.w + pv.w + bias2; t = (t >= 0.f) ? t : aP * t; r.w = t + bias3;
    *(float4*)(out + obase) = r;
}

// ---------------- launch ----------------
extern "C" void kernel_launch(void* const* d_in, const int* in_sizes, int n_in,
                              void* d_out, int out_size, void* d_ws, size_t ws_size,
                              hipStream_t stream) {
    const float* c       = (const float*)d_in[0];
    const float* x       = (const float*)d_in[1];
    const float* emb     = (const float*)d_in[2];
    const float* gn1_g   = (const float*)d_in[3];
    const float* gn1_b   = (const float*)d_in[4];
    const float* conv1_w = (const float*)d_in[5];
    const float* conv1_b = (const float*)d_in[6];
    const float* emb_w   = (const float*)d_in[7];
    const float* emb_b   = (const float*)d_in[8];
    const float* gn2_g   = (const float*)d_in[9];
    const float* gn2_b   = (const float*)d_in[10];
    const float* conv2_w = (const float*)d_in[11];
    const float* conv2_b = (const float*)d_in[12];
    const float* m1_w    = (const float*)d_in[13];
    const float* m1_b    = (const float*)d_in[14];
    const float* bconv_w = (const float*)d_in[15];
    const float* bconv_b = (const float*)d_in[16];
    const float* bn_g    = (const float*)d_in[17];
    const float* bn_b    = (const float*)d_in[18];
    const float* m2_w    = (const float*)d_in[19];
    const float* m2_b    = (const float*)d_in[20];
    const float* prelu_a = (const float*)d_in[21];
    const float* m3_w    = (const float*)d_in[22];
    const float* m3_b    = (const float*)d_in[23];
    float* out = (float*)d_out;

    // ws (~41.2 MB): poolC2 8.4MB (in a_buf slot) | y_buf 16MB |
    //                actA(bf16)/S(i8) aliased 8MB | sgn | Wc1 | Wc2 | small vecs
    float* ws = (float*)d_ws;
    const size_t NCHW = (size_t)B_ * C_ * HW_;       // 4,194,304
    float*  poolC2 = ws;                                        // 8.4 MB used
    float*  y_buf = ws + NCHW;
    unsigned short* actA = (unsigned short*)(ws + 2 * NCHW);   // 8 MB (NHWC bf16)
    int8_t* S     = (int8_t*)(ws + 2 * NCHW);                  // aliases actA
    int8_t* sgn   = (int8_t*)(ws + 2 * NCHW + NCHW / 2);       // 294912 B
    unsigned short* Wc1 = (unsigned short*)(ws + 2 * NCHW + NCHW / 2 + 73728);
    unsigned short* Wc2 = Wc1 + C_ * C_ * 9;                   // each 294912 B
    float*  alpha = ws + 2 * NCHW + NCHW / 2 + 73728 + 2 * 73728;
    float*  eo    = alpha + 128;
    float*  b1v   = eo + B_ * 256;
    float*  b2v   = b1v + B_ * 256;
    float*  b3v   = b2v + B_ * 128;
    float*  bnS   = b3v + B_ * 128;
    float*  bnQ   = bnS + 128;
    float*  gnS   = bnQ + 128;   // 256
    float*  gnQ   = gnS + 256;   // 256

    k_prep<<<1152, 256, 0, stream>>>(bconv_w, sgn, alpha, bnS, bnQ, gnS, gnQ,
                                     conv1_w, conv2_w, Wc1, Wc2,
                                     emb, emb_w, emb_b, m1_w, m1_b, m2_w, m2_b,
                                     m3_w, m3_b, eo, b1v, b2v, b3v,
                                     c, gn1_g, gn1_b, actA);
    k_conv1<<<dim3(64, B_), 256, 0, stream>>>(actA, Wc1, conv1_b, y_buf, gnS, gnQ);
    k_conv2<<<dim3(64, B_), 256, 0, stream>>>(y_buf, Wc2, conv2_b, c, x, b1v, eo,
                                              gn2_g, gn2_b, gnS, gnQ, poolC2, S);
    k_bconv<<<dim3(64, B_), 256, 0, stream>>>(S, sgn, alpha, bconv_b, y_buf, bnS, bnQ);
    k_final<<<NCHW / 1024, 256, 0, stream>>>(y_buf, x, poolC2, bnS, bnQ, bn_g, bn_b,
                                             b2v, prelu_a, b3v, out);
}